// Round 3
// baseline (369.931 us; speedup 1.0000x reference)
//
#include <hip/hip_runtime.h>
#include <stdint.h>

#define NF 8192
#define NX 2048
#define MROWS 8192
#define NGROUPS 32
#define NTILE 64   // NX/32 K-tiles

typedef unsigned short u16;
typedef __bf16 bf16x8 __attribute__((ext_vector_type(8)));
typedef float f32x16 __attribute__((ext_vector_type(16)));

#define AS1 __attribute__((address_space(1)))
#define AS3 __attribute__((address_space(3)))

// async global->LDS, 16B/lane; LDS dest = wave-uniform base + lane*16.
__device__ __forceinline__ void glds16(const void* g, void* l) {
    __builtin_amdgcn_global_load_lds((AS1 void*)(uintptr_t)g,
                                     (AS3 void*)(uintptr_t)l, 16, 0, 0);
}

__device__ __forceinline__ u16 f2bf(float f) {
    unsigned u = __float_as_uint(f);
    return (u16)((u + 0x7FFFu + ((u >> 16) & 1u)) >> 16);  // RNE
}

// packed [NF, NX/2] (one byte per int32, two nibbles) -> W bf16 [NF, NX] row-major.
__global__ void dequant_kernel(const int* __restrict__ packed,
                               const float* __restrict__ scales,
                               const int* __restrict__ zeros,
                               uint32_t* __restrict__ W2) {
    int tid = blockIdx.x * blockDim.x + threadIdx.x;   // [0, NF*NX/2)
    int f = tid >> 10;          // NX/2 = 1024 per row
    int i = tid & 1023;
    int g = f * NGROUPS + (i >> 5);
    int p = packed[tid];
    float s = scales[g];
    float z = (float)zeros[g];
    float w0 = ((float)(p & 15) - z) * s;
    float w1 = ((float)((p >> 4) & 15) - z) * s;
    W2[tid] = (uint32_t)f2bf(w0) | ((uint32_t)f2bf(w1) << 16);
}

// x fp32 -> bf16, 4 elems/thread
__global__ void cvt_kernel(const float4* __restrict__ x, ushort4* __restrict__ y) {
    int i = blockIdx.x * blockDim.x + threadIdx.x;
    float4 v = x[i];
    ushort4 o;
    o.x = f2bf(v.x); o.y = f2bf(v.y); o.z = f2bf(v.z); o.w = f2bf(v.w);
    y[i] = o;
}

// ===========================================================================
// 128x256 tile, BK=32, 8 waves (2Mx4N, 64x64/wave), mfma_f32_32x32x16_bf16.
// Sized for TWO blocks per CU (4 waves/SIMD): LDS 3 x 24KiB = 72KiB/block,
// VGPR budget ~115/wave (acc 64 + frags 32 + addr).  Cross-block TLP fills
// barrier/lgkm stalls (m114).  One barrier per phase; register frag reads
// pipelined one K-step ahead; stages 2 tiles ahead into a 3-deep LDS ring
// with counted vmcnt(3) (never 0 until the tail).
//
// LDS buffer (24 KiB): A at +0 (128 rows x 32k), B at +8192 (256 rows x 32k).
// Two block-rows packed per 128B LDS row; 16B units swizzled u ^= (ldsrow&7).
//   write: thread t -> LDS unit t (linear, glds-legal); its global source is
//          block-row 2*(t>>3)+(ulog>>2), k-slot ulog&3, ulog=(t&7)^((t>>3)&7).
//   read:  block-row r, k-slot s: LDS row r>>1, unit ((r&1)*4+s)^((r>>1)&7).
//   -> per 8-lane group all 8 units distinct (verified): conflict-free.
//
// Phase schedule (2 phases per K-tile, step s = 2T+K):
//   even (step 2T):  BAR; lgkm0; read frags step 2T+1 (bank O, bufC);
//                    stage tile T+2 -> bufT (3 glds, after BAR = WAR-safe:
//                    bufT's last readers passed their lgkm0 before this BAR);
//                    MFMA bank E.
//   odd (step 2T+1): vmcnt(3) [T+1's stages done; T+2's 3 stay in flight];
//                    BAR; lgkm0; read frags step 2T+2 (bank E, bufN);
//                    MFMA bank O.  rotate (bufC,bufN,bufT).
// Tail: T>=62 stages skipped; odd-phase wait becomes vmcnt(0).
// ===========================================================================

#define BAR    __builtin_amdgcn_s_barrier()
#define LGKM0  asm volatile("s_waitcnt lgkmcnt(0)" ::: "memory")
#define VMCNT3 asm volatile("s_waitcnt vmcnt(3)" ::: "memory")
#define VMCNT0 asm volatile("s_waitcnt vmcnt(0)" ::: "memory")
#define FENCE  __builtin_amdgcn_sched_barrier(0)

#define LD8(off) (*(const bf16x8*)(smem + (off)))

#define MFMA32(d, va, vb) d = __builtin_amdgcn_mfma_f32_32x32x16_bf16(va, vb, d, 0, 0, 0)

#define RDBANK(aX, bX, BUF, U) do { \
    aX[0] = LD8((BUF) + aR0 + (U)); \
    aX[1] = LD8((BUF) + aR1 + (U)); \
    bX[0] = LD8((BUF) + bR0 + (U)); \
    bX[1] = LD8((BUF) + bR1 + (U)); \
} while (0)

#define MM2(aX, bX) do { \
    MFMA32(acc[0][0], aX[0], bX[0]); \
    MFMA32(acc[0][1], aX[0], bX[1]); \
    MFMA32(acc[1][0], aX[1], bX[0]); \
    MFMA32(acc[1][1], aX[1], bX[1]); \
} while (0)

#define STAGE3(BUF, KOFF) do { \
    glds16(srcA  + (KOFF), smem + (BUF) + t16); \
    glds16(srcB0 + (KOFF), smem + (BUF) + 8192 + t16); \
    glds16(srcB1 + (KOFF), smem + (BUF) + 16384 + t16); \
} while (0)

__global__ __launch_bounds__(512, 4)
void gemm_kernel(const u16* __restrict__ A, const u16* __restrict__ B,
                 const float* __restrict__ bias, float* __restrict__ C) {
    __shared__ __align__(16) char smem[73728];   // 3 x 24 KiB ring

    const int t = threadIdx.x;

    // T1: bijective XCD swizzle (2048 blocks % 8 == 0). 64 M-tiles x 32 N-tiles;
    // consecutive in-XCD ids walk N fast (shared 512 KiB A-panel -> L2 hits).
    const int bid = blockIdx.x;
    const int swz = (bid & 7) * 256 + (bid >> 3);
    const int by = swz >> 5;          // 0..63  M-tile
    const int bx = swz & 31;          // 0..31  N-tile
    const int rowA0 = by * 128;
    const int rowB0 = bx * 256;

    // ---- staging addressing (inverse-swizzled global source, linear LDS) ----
    const int t16 = t * 16;
    const int ulog = (t & 7) ^ ((t >> 3) & 7);
    const int brow = 2 * (t >> 3) + (ulog >> 2);
    const int ks16 = (ulog & 3) * 16;
    const char* srcA  = (const char*)A + (size_t)(rowA0 + brow) * 4096 + ks16;
    const char* srcB0 = (const char*)B + (size_t)(rowB0 + brow) * 4096 + ks16;
    const char* srcB1 = srcB0 + (size_t)128 * 4096;

    // ---- fragment read addressing (swizzled) ----
    const int lane = t & 63;
    const int wv = t >> 6;
    const int wm = wv >> 2;            // 0..1 (M half, 64 rows)
    const int wn = wv & 3;             // 0..3 (N quarter, 64 cols)
    const int l31 = lane & 31;
    const int hi = lane >> 5;          // k-group
    const int lh = l31 >> 1;
    const int x7 = lh & 7;
    const int ux4 = (l31 & 1) * 4;
    const int u0 = ((ux4 + 0 + hi) ^ x7) * 16;   // K-step 0 unit offset
    const int u1 = ((ux4 + 2 + hi) ^ x7) * 16;   // K-step 1 unit offset
    const int aR0 = (wm * 32 + lh) * 128;        // A region LDS-row byte off
    const int aR1 = aR0 + 16 * 128;
    const int bR0 = 8192 + (wn * 32 + lh) * 128; // B region
    const int bR1 = bR0 + 16 * 128;

    f32x16 acc[2][2];
#pragma unroll
    for (int i = 0; i < 2; ++i)
#pragma unroll
        for (int n = 0; n < 2; ++n)
#pragma unroll
            for (int r = 0; r < 16; ++r) acc[i][n][r] = 0.f;

    bf16x8 aE[2], bE[2], aO[2], bO[2];

    // ---- prologue: stage T0->buf0, T1->buf1; wait T0; read step0 (bank E) ----
    STAGE3(0,     0);
    STAGE3(24576, 64);
    VMCNT3;            // T0's 3 done; T1's 3 in flight
    BAR;
    RDBANK(aE, bE, 0, u0);

    int bufC = 0, bufN = 24576, bufT = 49152;
    int kOff = 128;    // byte K-offset of tile T+2

#pragma unroll 1
    for (int T = 0; T < NTILE; ++T) {
        // ---------- even phase: step 2T (bank E) ----------
        FENCE; BAR; LGKM0; FENCE;
        RDBANK(aO, bO, bufC, u1);                 // frags for step 2T+1
        if (T < NTILE - 2) STAGE3(bufT, kOff);    // tile T+2 (WAR-safe post-BAR)
        __builtin_amdgcn_s_setprio(1);
        MM2(aE, bE);
        __builtin_amdgcn_s_setprio(0);
        FENCE;

        // ---------- odd phase: step 2T+1 (bank O) ----------
        if (T < NTILE - 2) VMCNT3; else VMCNT0;   // T+1's stages landed
        BAR; LGKM0; FENCE;
        if (T < NTILE - 1) RDBANK(aE, bE, bufN, u0);  // step 2T+2 (tile T+1)
        __builtin_amdgcn_s_setprio(1);
        MM2(aO, bO);
        __builtin_amdgcn_s_setprio(0);
        FENCE;

        const int tmp = bufC; bufC = bufN; bufN = bufT; bufT = tmp;
        kOff += 64;
    }

    // ---- epilogue: C/D col = l31, row = (r&3) + 8*(r>>2) + 4*hi ----
    const int col0 = rowB0 + wn * 64 + l31;
    const int row0 = rowA0 + wm * 64 + 4 * hi;
    const float bj0 = bias[col0];
    const float bj1 = bias[col0 + 32];
    float* Cbase = C + col0;
#pragma unroll
    for (int i = 0; i < 2; ++i) {
#pragma unroll
        for (int r = 0; r < 16; ++r) {
            const int row = row0 + i * 32 + (r & 3) + 8 * (r >> 2);
            float* crow = Cbase + (size_t)row * NF;
            __builtin_nontemporal_store(acc[i][0][r] + bj0, crow);
            __builtin_nontemporal_store(acc[i][1][r] + bj1, crow + 32);
        }
    }
}

extern "C" void kernel_launch(void* const* d_in, const int* in_sizes, int n_in,
                              void* d_out, int out_size, void* d_ws, size_t ws_size,
                              hipStream_t stream) {
    const float* x      = (const float*)d_in[0];   // [4,2048,2048] fp32
    const int* packed   = (const int*)d_in[1];     // [8192,1024]
    const float* scales = (const float*)d_in[2];   // [8192,32]
    const int* zeros    = (const int*)d_in[3];     // [8192,32]
    const float* bias   = (const float*)d_in[4];   // [8192]
    float* out = (float*)d_out;                    // [8192, 8192] fp32

    // workspace: W bf16 (32 MiB) + x bf16 (32 MiB); fully rewritten every call
    u16* Wq = (u16*)d_ws;
    u16* Xb = Wq + (size_t)NF * NX;

    dequant_kernel<<<(NF * (NX / 2)) / 256, 256, 0, stream>>>(packed, scales, zeros, (uint32_t*)Wq);
    cvt_kernel<<<(MROWS * NX / 4) / 256, 256, 0, stream>>>((const float4*)x, (ushort4*)Xb);

    gemm_kernel<<<dim3((MROWS / 128) * (NF / 256)), 512, 0, stream>>>(Xb, Wq, bias, out);
}

// Round 4
// 330.038 us; speedup vs baseline: 1.1209x; 1.1209x over previous
//
#include <hip/hip_runtime.h>
#include <stdint.h>

#define NF 8192
#define NX 2048
#define MROWS 8192
#define NGROUPS 32
#define NTILE 64   // NX/32 K-tiles

typedef unsigned short u16;
typedef __bf16 bf16x8 __attribute__((ext_vector_type(8)));
typedef float f32x16 __attribute__((ext_vector_type(16)));

#define AS1 __attribute__((address_space(1)))
#define AS3 __attribute__((address_space(3)))

// async global->LDS, 16B/lane; LDS dest = wave-uniform base + lane*16.
__device__ __forceinline__ void glds16(const void* g, void* l) {
    __builtin_amdgcn_global_load_lds((AS1 void*)(uintptr_t)g,
                                     (AS3 void*)(uintptr_t)l, 16, 0, 0);
}

__device__ __forceinline__ u16 f2bf(float f) {
    unsigned u = __float_as_uint(f);
    return (u16)((u + 0x7FFFu + ((u >> 16) & 1u)) >> 16);  // RNE
}

// packed [NF, NX/2] (one byte per int32, two nibbles) -> W bf16 [NF, NX] row-major.
__global__ void dequant_kernel(const int* __restrict__ packed,
                               const float* __restrict__ scales,
                               const int* __restrict__ zeros,
                               uint32_t* __restrict__ W2) {
    int tid = blockIdx.x * blockDim.x + threadIdx.x;   // [0, NF*NX/2)
    int f = tid >> 10;          // NX/2 = 1024 per row
    int i = tid & 1023;
    int g = f * NGROUPS + (i >> 5);
    int p = packed[tid];
    float s = scales[g];
    float z = (float)zeros[g];
    float w0 = ((float)(p & 15) - z) * s;
    float w1 = ((float)((p >> 4) & 15) - z) * s;
    W2[tid] = (uint32_t)f2bf(w0) | ((uint32_t)f2bf(w1) << 16);
}

// x fp32 -> bf16, 4 elems/thread
__global__ void cvt_kernel(const float4* __restrict__ x, ushort4* __restrict__ y) {
    int i = blockIdx.x * blockDim.x + threadIdx.x;
    float4 v = x[i];
    ushort4 o;
    o.x = f2bf(v.x); o.y = f2bf(v.y); o.z = f2bf(v.z); o.w = f2bf(v.w);
    y[i] = o;
}

// ===========================================================================
// 256x128 tile, BK=32, 8 waves (4Mx2N, 64x64/wave), mfma_f32_32x32x16_bf16.
// TWO blocks per CU (4 waves/SIMD): LDS dbuf 2 x 24 KiB = 48 KiB/block,
// ~120 unified VGPR/wave (acc 64 in AGPR + frags 32 + addr). Cross-block
// TLP fills barrier/lgkm stalls (m114). ONE barrier + one per-wave
// vmcnt(0) per K-tile; frag reads double-banked (E=k0..15, O=k16..31).
//
// LDS buffer (24 KiB): A at +0 (256 rows x 32k), B at +16384 (128 rows).
// Rows are 64 B; packed 2 rows per 128B LDS line. 16B units within a line
// swizzled phys = logical ^ (line&7), logical = (row&1)*4 + (2*ks + hi).
//   write: glds linear (unit U = thread t [+512]); source decodes
//          logical = (U&7)^((U>>3)&7): row = 2*(U>>3)+(logical>>2),
//          k-slot = logical&3.
//   read:  per-8-lane bank walk verified all-distinct (conflict-free) for
//          both hi halves and both ks banks.
//
// Per K-tile T (bo = active buf, so = other):
//   BAR                       // T's stages visible (each wave vmcnt0'd at T-1
//                             // end); so's T-1 readers all drained pre-BAR
//   read E-frags (bo, k0-15); issue 3 glds: tile T+1 -> so
//   lgkm0; read O-frags (bo, k16-31)
//   MFMA(E)  [setprio 1]
//   lgkm0; MFMA(O)  [setprio 1]
//   vmcnt(0)                  // own stages for T+1 done; BAR@T+1 makes all visible
// Hazards: WAR on so -- its last readers (T-1's O-reads) lgkm-drained before
// their MFMA, hence before this BAR, chip-wide. RAW on so -- per-wave
// vmcnt(0) then BAR. Within-tile reads target bo only (no write to bo).
// ===========================================================================

#define BAR    __builtin_amdgcn_s_barrier()
#define LGKM0  asm volatile("s_waitcnt lgkmcnt(0)" ::: "memory")
#define VMCNT0 asm volatile("s_waitcnt vmcnt(0)" ::: "memory")
#define FENCE  __builtin_amdgcn_sched_barrier(0)

#define LD8(off) (*(const bf16x8*)(smem + (off)))

#define MFMA32(d, va, vb) d = __builtin_amdgcn_mfma_f32_32x32x16_bf16(va, vb, d, 0, 0, 0)

#define RDBANK(aX, bX, BUF, U) do { \
    aX[0] = LD8((BUF) + aOff + (U)); \
    aX[1] = LD8((BUF) + aOff + 2048 + (U)); \
    bX[0] = LD8((BUF) + bOff + (U)); \
    bX[1] = LD8((BUF) + bOff + 2048 + (U)); \
} while (0)

#define MM2(aX, bX) do { \
    MFMA32(acc[0][0], aX[0], bX[0]); \
    MFMA32(acc[0][1], aX[0], bX[1]); \
    MFMA32(acc[1][0], aX[1], bX[0]); \
    MFMA32(acc[1][1], aX[1], bX[1]); \
} while (0)

#define STAGE3(BUF, KOFF) do { \
    glds16(srcA + (KOFF),          smem + (BUF) + t16); \
    glds16(srcA + 524288 + (KOFF), smem + (BUF) + 8192 + t16); \
    glds16(srcB + (KOFF),          smem + (BUF) + 16384 + t16); \
} while (0)

__global__ __launch_bounds__(512, 4)
void gemm_kernel(const u16* __restrict__ A, const u16* __restrict__ B,
                 const float* __restrict__ bias, float* __restrict__ C) {
    __shared__ __align__(16) char smem[49152];   // 2 x 24 KiB

    const int t = threadIdx.x;

    // T1: 2-D striped XCD swizzle. Grid 2048 = 32 by x 64 bx. Each XCD owns
    // 4 by-rows as 2 supers of (2 by x 64 bx), by fastest: the ~64 concurrent
    // blocks/XCD touch 2 A-panels + 32 B-panels (~288 KiB hot/K-tile -> L2).
    const int bid = blockIdx.x;
    const int xcd = bid & 7;
    const int local = bid >> 3;          // 0..255
    const int super = local >> 7;        // 0..1
    const int r = local & 127;
    const int by = xcd * 4 + super * 2 + (r & 1);   // 0..31
    const int bx = r >> 1;                          // 0..63
    const int rowA0 = by * 256;
    const int rowB0 = bx * 128;

    // ---- staging addressing (inverse-swizzled global source, linear LDS) ----
    const int t16 = t * 16;
    const int ulog = (t & 7) ^ ((t >> 3) & 7);
    const int urow = 2 * (t >> 3) + (ulog >> 2);   // 0..127
    const int ks16 = (ulog & 3) * 16;
    const char* srcA = (const char*)A + (size_t)(rowA0 + urow) * 4096 + ks16;
    const char* srcB = (const char*)B + (size_t)(rowB0 + urow) * 4096 + ks16;

    // ---- fragment read addressing (swizzled) ----
    const int lane = t & 63;
    const int wv = t >> 6;
    const int wm = wv >> 1;            // 0..3 (M quarter, 64 rows)
    const int wn = wv & 1;             // 0..1 (N half, 64 cols)
    const int l31 = lane & 31;
    const int hi = lane >> 5;          // k-group (0/1)
    const int lh = l31 >> 1;
    const int x7 = lh & 7;
    const int ux4 = (l31 & 1) * 4;
    const int u0 = ((ux4 + hi) ^ x7) << 4;        // K16-step 0 unit offset
    const int u1 = ((ux4 + 2 + hi) ^ x7) << 4;    // K16-step 1 unit offset
    const int aOff = (wm * 32 + lh) * 128;        // A LDS line byte offset
    const int bOff = 16384 + (wn * 32 + lh) * 128;

    f32x16 acc[2][2];
#pragma unroll
    for (int i = 0; i < 2; ++i)
#pragma unroll
        for (int n = 0; n < 2; ++n)
#pragma unroll
            for (int e = 0; e < 16; ++e) acc[i][n][e] = 0.f;

    bf16x8 aE[2], bE[2], aO[2], bO[2];

    // ---- prologue: stage tile0 -> buf0, per-wave drain ----
    STAGE3(0, 0);
    VMCNT0;

#pragma unroll 1
    for (int T = 0; T < NTILE; ++T) {
        const int bo = (T & 1) * 24576;   // active buffer
        const int so = 24576 - bo;        // inactive (receives T+1)

        FENCE; BAR; FENCE;
        RDBANK(aE, bE, bo, u0);
        if (T + 1 < NTILE) STAGE3(so, (T + 1) * 64);
        FENCE; LGKM0; FENCE;              // E-frags ready (glds are vmcnt)
        RDBANK(aO, bO, bo, u1);
        FENCE;
        __builtin_amdgcn_s_setprio(1);
        MM2(aE, bE);
        __builtin_amdgcn_s_setprio(0);
        FENCE; LGKM0; FENCE;              // O-frags ready
        __builtin_amdgcn_s_setprio(1);
        MM2(aO, bO);
        __builtin_amdgcn_s_setprio(0);
        FENCE;
        VMCNT0;                           // own 3 stages for T+1 landed
    }

    // ---- epilogue: C/D col = l31, row = (e&3) + 8*(e>>2) + 4*hi ----
    const int col0 = rowB0 + wn * 64 + l31;
    const int row0 = rowA0 + wm * 64 + 4 * hi;
    const float bj0 = bias[col0];
    const float bj1 = bias[col0 + 32];
    float* Cbase = C + col0;
#pragma unroll
    for (int i = 0; i < 2; ++i) {
#pragma unroll
        for (int e = 0; e < 16; ++e) {
            const int row = row0 + i * 32 + (e & 3) + 8 * (e >> 2);
            float* crow = Cbase + (size_t)row * NF;
            __builtin_nontemporal_store(acc[i][0][e] + bj0, crow);
            __builtin_nontemporal_store(acc[i][1][e] + bj1, crow + 32);
        }
    }
}

extern "C" void kernel_launch(void* const* d_in, const int* in_sizes, int n_in,
                              void* d_out, int out_size, void* d_ws, size_t ws_size,
                              hipStream_t stream) {
    const float* x      = (const float*)d_in[0];   // [4,2048,2048] fp32
    const int* packed   = (const int*)d_in[1];     // [8192,1024]
    const float* scales = (const float*)d_in[2];   // [8192,32]
    const int* zeros    = (const int*)d_in[3];     // [8192,32]
    const float* bias   = (const float*)d_in[4];   // [8192]
    float* out = (float*)d_out;                    // [8192, 8192] fp32

    // workspace: W bf16 (32 MiB) + x bf16 (32 MiB); fully rewritten every call
    u16* Wq = (u16*)d_ws;
    u16* Xb = Wq + (size_t)NF * NX;

    dequant_kernel<<<(NF * (NX / 2)) / 256, 256, 0, stream>>>(packed, scales, zeros, (uint32_t*)Wq);
    cvt_kernel<<<(MROWS * NX / 4) / 256, 256, 0, stream>>>((const float4*)x, (ushort4*)Xb);

    gemm_kernel<<<dim3((MROWS / 256) * (NF / 128)), 512, 0, stream>>>(Xb, Wq, bias, out);
}

// Round 5
// 329.984 us; speedup vs baseline: 1.1211x; 1.0002x over previous
//
#include <hip/hip_runtime.h>
#include <stdint.h>

#define NF 8192
#define NX 2048
#define MROWS 8192
#define NGROUPS 32
#define NTILE 64   // NX/32 K-tiles

typedef unsigned short u16;
typedef __bf16 bf16x8 __attribute__((ext_vector_type(8)));
typedef float f32x16 __attribute__((ext_vector_type(16)));

#define AS1 __attribute__((address_space(1)))
#define AS3 __attribute__((address_space(3)))

// async global->LDS, 16B/lane; LDS dest = wave-uniform base + lane*16.
__device__ __forceinline__ void glds16(const void* g, void* l) {
    __builtin_amdgcn_global_load_lds((AS1 void*)(uintptr_t)g,
                                     (AS3 void*)(uintptr_t)l, 16, 0, 0);
}

__device__ __forceinline__ u16 f2bf(float f) {
    unsigned u = __float_as_uint(f);
    return (u16)((u + 0x7FFFu + ((u >> 16) & 1u)) >> 16);  // RNE
}

// packed [NF, NX/2] (one byte per int32, two nibbles) -> W bf16 [NF, NX] row-major.
__global__ void dequant_kernel(const int* __restrict__ packed,
                               const float* __restrict__ scales,
                               const int* __restrict__ zeros,
                               uint32_t* __restrict__ W2) {
    int tid = blockIdx.x * blockDim.x + threadIdx.x;   // [0, NF*NX/2)
    int f = tid >> 10;          // NX/2 = 1024 per row
    int i = tid & 1023;
    int g = f * NGROUPS + (i >> 5);
    int p = packed[tid];
    float s = scales[g];
    float z = (float)zeros[g];
    float w0 = ((float)(p & 15) - z) * s;
    float w1 = ((float)((p >> 4) & 15) - z) * s;
    W2[tid] = (uint32_t)f2bf(w0) | ((uint32_t)f2bf(w1) << 16);
}

// x fp32 -> bf16, 4 elems/thread
__global__ void cvt_kernel(const float4* __restrict__ x, ushort4* __restrict__ y) {
    int i = blockIdx.x * blockDim.x + threadIdx.x;
    float4 v = x[i];
    ushort4 o;
    o.x = f2bf(v.x); o.y = f2bf(v.y); o.z = f2bf(v.z); o.w = f2bf(v.w);
    y[i] = o;
}

// ===========================================================================
// 256x128 tile, BK=32, 8 waves (4Mx2N, 64x64/wave), mfma_f32_32x32x16_bf16.
// TWO blocks per CU (4 waves/SIMD): LDS ring-3 x 24 KiB = 72 KiB/block,
// ~124 unified VGPR/wave. ONE barrier + one counted vmcnt per K-tile;
// stages 2 tiles ahead (vmcnt(3), never 0 until the tail).
//
// LDS buffer (24 KiB): A at +0 (256 rows, 128 lines), B at +16384 (128 rows,
// 64 lines). Line = 128 B holding row pair (r, r+64) [A chunk2: +128].
// CONFLICT RULE (empirical, R1 measured 0 vs R3/R4 saturated): consecutive
// lanes must read consecutive LINES; 16B unit swizzled by line&7.
//   unit logical = ugrp*4 + kslot, ugrp = (row>=64 in pair), kslot = k-16B
//   slot (0..3) of the row's 64B; phys = logical ^ (line&7).
//   write: glds linear unit U=t: line=U>>3, phys=U&7, logical=phys^(line&7),
//          source row = (t>>3) + (logical>>2)*64 [+128 chunk2], k=logical&3.
//   read (A, instance i, wave wm): line = (wm>>1)*64 + i*32 + l31,
//          phys = ((wm&1)*4 + 2ks + hi) ^ (l31&7)   -> lanes 0..31 hit 32
//          distinct consecutive lines, unit = c ^ (l31&7): R1's exact form.
//   read (B, instance n, wave wn): line = n*32 + l31, phys = (wn*4+2ks+hi)^(l31&7).
//
// Per K-tile T (bufC=consume T, bufN=T+1 landing, bufT=stage T+2 target):
//   BAR                      // T's data visible (all waves vmcnt'd T at end
//                            // of T-1... completes stages-for-(T+1)? see below)
//   read E-frags (bufC,k0-15); stage T+2 -> bufT (3 glds, post-BAR: WAR-safe,
//                            bufT's readers drained lgkm before T's BAR)
//   lgkm0; read O-frags (bufC,k16-31); MFMA(E); lgkm0; MFMA(O)
//   vmcnt(3)                 // completes stages-for-(T+1); T+2's 3 in flight
// RAW: tile T's data staged at T-2, own-wave confirmed by vmcnt(3)@end(T-2),
// cross-wave visible via BAR@T-1 and BAR@T.  Tail: T=NTILE-2 -> vmcnt(0).
// ===========================================================================

#define BAR    __builtin_amdgcn_s_barrier()
#define LGKM0  asm volatile("s_waitcnt lgkmcnt(0)" ::: "memory")
#define VMCNT3 asm volatile("s_waitcnt vmcnt(3)" ::: "memory")
#define VMCNT0 asm volatile("s_waitcnt vmcnt(0)" ::: "memory")
#define FENCE  __builtin_amdgcn_sched_barrier(0)

#define LD8(off) (*(const bf16x8*)(smem + (off)))

#define MFMA32(d, va, vb) d = __builtin_amdgcn_mfma_f32_32x32x16_bf16(va, vb, d, 0, 0, 0)

#define RDBANK(aX, bX, BUF, UA, UB) do { \
    aX[0] = LD8((BUF) + aOff + (UA)); \
    aX[1] = LD8((BUF) + aOff + 4096 + (UA)); \
    bX[0] = LD8((BUF) + bOff + (UB)); \
    bX[1] = LD8((BUF) + bOff + 4096 + (UB)); \
} while (0)

#define MM2(aX, bX) do { \
    MFMA32(acc[0][0], aX[0], bX[0]); \
    MFMA32(acc[0][1], aX[0], bX[1]); \
    MFMA32(acc[1][0], aX[1], bX[0]); \
    MFMA32(acc[1][1], aX[1], bX[1]); \
} while (0)

#define STAGE3(BUF, KOFF) do { \
    glds16(srcA + (KOFF),          smem + (BUF) + t16); \
    glds16(srcA + 524288 + (KOFF), smem + (BUF) + 8192 + t16); \
    glds16(srcB + (KOFF),          smem + (BUF) + 16384 + t16); \
} while (0)

__global__ __launch_bounds__(512, 4)
void gemm_kernel(const u16* __restrict__ A, const u16* __restrict__ B,
                 const float* __restrict__ bias, float* __restrict__ C) {
    __shared__ __align__(16) char smem[73728];   // 3 x 24 KiB ring

    const int t = threadIdx.x;

    // T1: 2-D striped XCD swizzle (R4-proven: FETCH 295 MB). Grid 2048 =
    // 32 by x 64 bx; each XCD owns 4 by-rows as 2 supers of (2 by x 64 bx).
    const int bid = blockIdx.x;
    const int xcd = bid & 7;
    const int local = bid >> 3;          // 0..255
    const int super = local >> 7;        // 0..1
    const int r = local & 127;
    const int by = xcd * 4 + super * 2 + (r & 1);   // 0..31
    const int bx = r >> 1;                          // 0..63
    const int rowA0 = by * 256;
    const int rowB0 = bx * 128;

    // ---- staging addressing (inverse-swizzled global source, linear LDS) ----
    const int t16 = t * 16;
    const int ulog = (t & 7) ^ ((t >> 3) & 7);
    const int urow = (t >> 3) + (ulog >> 2) * 64;  // 0..127 (chunk2: +128)
    const int ks16 = (ulog & 3) * 16;
    const char* srcA = (const char*)A + (size_t)(rowA0 + urow) * 4096 + ks16;
    const char* srcB = (const char*)B + (size_t)(rowB0 + urow) * 4096 + ks16;

    // ---- fragment read addressing (swizzled; lanes -> distinct lines) ----
    const int lane = t & 63;
    const int wv = t >> 6;
    const int wm = wv >> 1;            // 0..3 (M quarter, 64 rows)
    const int wn = wv & 1;             // 0..1 (N half, 64 cols)
    const int l31 = lane & 31;
    const int hi = lane >> 5;          // k-group (0/1)
    const int xl = l31 & 7;
    const int am = (wm & 1) * 4;
    const int bm = wn * 4;
    const int uA0 = ((am + hi) ^ xl) << 4;        // A unit, K16-step 0
    const int uA1 = ((am + 2 + hi) ^ xl) << 4;    // A unit, K16-step 1
    const int uB0 = ((bm + hi) ^ xl) << 4;
    const int uB1 = ((bm + 2 + hi) ^ xl) << 4;
    const int aOff = ((wm >> 1) * 64 + l31) * 128;     // A line byte offset
    const int bOff = 16384 + l31 * 128;                // B line byte offset

    f32x16 acc[2][2];
#pragma unroll
    for (int i = 0; i < 2; ++i)
#pragma unroll
        for (int n = 0; n < 2; ++n)
#pragma unroll
            for (int e = 0; e < 16; ++e) acc[i][n][e] = 0.f;

    bf16x8 aE[2], bE[2], aO[2], bO[2];

    // ---- prologue: stage T0->buf0, T1->buf1; vmcnt(3) completes T0 ----
    STAGE3(0,     0);
    STAGE3(24576, 64);
    VMCNT3;

    int bufC = 0, bufN = 24576, bufT = 49152;
    int kOff = 128;    // byte K-offset of tile T+2

#pragma unroll 1
    for (int T = 0; T < NTILE; ++T) {
        FENCE; BAR; FENCE;
        RDBANK(aE, bE, bufC, uA0, uB0);
        if (T < NTILE - 2) STAGE3(bufT, kOff);     // tile T+2 (WAR-safe post-BAR)
        FENCE; LGKM0; FENCE;                       // E-frags ready (glds = vmcnt)
        RDBANK(aO, bO, bufC, uA1, uB1);
        FENCE;
        __builtin_amdgcn_s_setprio(1);
        MM2(aE, bE);
        __builtin_amdgcn_s_setprio(0);
        FENCE; LGKM0; FENCE;                       // O-frags ready
        __builtin_amdgcn_s_setprio(1);
        MM2(aO, bO);
        __builtin_amdgcn_s_setprio(0);
        FENCE;
        if (T < NTILE - 2) VMCNT3;                 // stages-for-(T+1) landed
        else if (T < NTILE - 1) VMCNT0;            // last in-flight unit

        const int tmp = bufC; bufC = bufN; bufN = bufT; bufT = tmp;
        kOff += 64;
    }

    // ---- epilogue: C/D col = l31, row = (e&3) + 8*(e>>2) + 4*hi ----
    const int col0 = rowB0 + wn * 64 + l31;
    const int row0 = rowA0 + wm * 64 + 4 * hi;
    const float bj0 = bias[col0];
    const float bj1 = bias[col0 + 32];
    float* Cbase = C + col0;
#pragma unroll
    for (int i = 0; i < 2; ++i) {
#pragma unroll
        for (int e = 0; e < 16; ++e) {
            const int row = row0 + i * 32 + (e & 3) + 8 * (e >> 2);
            float* crow = Cbase + (size_t)row * NF;
            __builtin_nontemporal_store(acc[i][0][e] + bj0, crow);
            __builtin_nontemporal_store(acc[i][1][e] + bj1, crow + 32);
        }
    }
}

extern "C" void kernel_launch(void* const* d_in, const int* in_sizes, int n_in,
                              void* d_out, int out_size, void* d_ws, size_t ws_size,
                              hipStream_t stream) {
    const float* x      = (const float*)d_in[0];   // [4,2048,2048] fp32
    const int* packed   = (const int*)d_in[1];     // [8192,1024]
    const float* scales = (const float*)d_in[2];   // [8192,32]
    const int* zeros    = (const int*)d_in[3];     // [8192,32]
    const float* bias   = (const float*)d_in[4];   // [8192]
    float* out = (float*)d_out;                    // [8192, 8192] fp32

    // workspace: W bf16 (32 MiB) + x bf16 (32 MiB); fully rewritten every call
    u16* Wq = (u16*)d_ws;
    u16* Xb = Wq + (size_t)NF * NX;

    dequant_kernel<<<(NF * (NX / 2)) / 256, 256, 0, stream>>>(packed, scales, zeros, (uint32_t*)Wq);
    cvt_kernel<<<(MROWS * NX / 4) / 256, 256, 0, stream>>>((const float4*)x, (ushort4*)Xb);

    gemm_kernel<<<dim3((MROWS / 256) * (NF / 128)), 512, 0, stream>>>(Xb, Wq, bias, out);
}

// Round 6
// 295.897 us; speedup vs baseline: 1.2502x; 1.1152x over previous
//
#include <hip/hip_runtime.h>
#include <stdint.h>

#define NF 8192
#define NX 2048
#define MROWS 8192
#define NGROUPS 32
#define NT 32   // NX/64 K-tiles

typedef unsigned short u16;
typedef __bf16 bf16x8 __attribute__((ext_vector_type(8)));
typedef float f32x4 __attribute__((ext_vector_type(4)));

#define AS1 __attribute__((address_space(1)))
#define AS3 __attribute__((address_space(3)))

// async global->LDS, 16B/lane; LDS dest = wave-uniform base + lane*16.
__device__ __forceinline__ void glds16(const void* g, void* l) {
    __builtin_amdgcn_global_load_lds((AS1 void*)(uintptr_t)g,
                                     (AS3 void*)(uintptr_t)l, 16, 0, 0);
}

__device__ __forceinline__ u16 f2bf(float f) {
    unsigned u = __float_as_uint(f);
    return (u16)((u + 0x7FFFu + ((u >> 16) & 1u)) >> 16);  // RNE
}

// packed [NF, NX/2] (one byte per int32, two nibbles) -> W bf16 [NF, NX] row-major.
__global__ void dequant_kernel(const int* __restrict__ packed,
                               const float* __restrict__ scales,
                               const int* __restrict__ zeros,
                               uint32_t* __restrict__ W2) {
    int tid = blockIdx.x * blockDim.x + threadIdx.x;   // [0, NF*NX/2)
    int f = tid >> 10;          // NX/2 = 1024 per row
    int i = tid & 1023;
    int g = f * NGROUPS + (i >> 5);
    int p = packed[tid];
    float s = scales[g];
    float z = (float)zeros[g];
    float w0 = ((float)(p & 15) - z) * s;
    float w1 = ((float)((p >> 4) & 15) - z) * s;
    W2[tid] = (uint32_t)f2bf(w0) | ((uint32_t)f2bf(w1) << 16);
}

// x fp32 -> bf16, 4 elems/thread
__global__ void cvt_kernel(const float4* __restrict__ x, ushort4* __restrict__ y) {
    int i = blockIdx.x * blockDim.x + threadIdx.x;
    float4 v = x[i];
    ushort4 o;
    o.x = f2bf(v.x); o.y = f2bf(v.y); o.z = f2bf(v.z); o.w = f2bf(v.w);
    y[i] = o;
}

// ===========================================================================
// 128x128 tile, BK=64, 256 threads (4 waves, 2Mx2N, 64x64/wave),
// mfma_f32_16x16x32_bf16.  TWO independent blocks per CU (LDS 64 KiB each;
// cross-block TLP fills stalls, m114).  ONE barrier + one vmcnt(0) per
// K-tile; frag reads double-banked (kk0+kk1 issued together, lgkmcnt(8)
// gates kk0's MFMA, lgkmcnt(0) gates kk1's).
//
// LDS (R1's measured-ZERO-conflict geometry, replicated exactly):
//   buffer 32 KiB: A at +0 (128 lines), B at +16384 (128 lines).
//   line = 128 B = one row's BK=64 bf16.  16-B unit: logical = kk*4+quad,
//   phys = logical ^ (line&7).
//   write: glds linear, unit U = t+256c: line = U>>3, phys = U&7; source
//     decodes ulog = (t&7)^((t>>3)&7) (32c drops mod 8): row = (t>>3)+32c,
//     koff = (ulog>>2)*64 + (ulog&3)*16.
//   read (16-lane period, quad-XOR — the empirically conflict-free form):
//     a[i]: line = wm*64 + i*16 + l15, phys = (kk*4+quad) ^ (l15&7)
//     b[j]: line = wn*64 + j*16 + l15, same phys form.
//
// Per K-tile T (bo = active, so = inactive):
//   BAR                      // T staged (all waves vmcnt0'd at T-1 end)
//   stage T+1 -> so (8 glds) // WAR-safe: so's readers drained pre-BAR
//   read kk0 (8 ds) bank0; read kk1 (8 ds) bank1
//   lgkmcnt(8); MFMA kk0 (16)     [setprio]
//   lgkmcnt(0); MFMA kk1 (16)     [setprio]
//   vmcnt(0)                 // own stages for T+1 landed
// ===========================================================================

#define BAR    __builtin_amdgcn_s_barrier()
#define LGKM8  asm volatile("s_waitcnt lgkmcnt(8)" ::: "memory")
#define LGKM0  asm volatile("s_waitcnt lgkmcnt(0)" ::: "memory")
#define VMCNT0 asm volatile("s_waitcnt vmcnt(0)" ::: "memory")
#define FENCE  __builtin_amdgcn_sched_barrier(0)

#define LD8(off) (*(const bf16x8*)(smem + (off)))

#define RD(aX, bX, BUF, SX) do { \
    _Pragma("unroll") \
    for (int i_ = 0; i_ < 4; ++i_) aX[i_] = LD8((BUF) + aOff + i_ * 2048 + (SX)); \
    _Pragma("unroll") \
    for (int j_ = 0; j_ < 4; ++j_) bX[j_] = LD8((BUF) + bOff + j_ * 2048 + (SX)); \
} while (0)

#define MM(aX, bX) do { \
    _Pragma("unroll") \
    for (int i_ = 0; i_ < 4; ++i_) \
        _Pragma("unroll") \
        for (int j_ = 0; j_ < 4; ++j_) \
            acc[i_][j_] = __builtin_amdgcn_mfma_f32_16x16x32_bf16(aX[i_], bX[j_], acc[i_][j_], 0, 0, 0); \
} while (0)

#define STAGE8(BUF, KOFF) do { \
    _Pragma("unroll") \
    for (int c_ = 0; c_ < 4; ++c_) \
        glds16(srcA + c_ * 131072 + (KOFF), smem + (BUF) + c_ * 4096 + t16); \
    _Pragma("unroll") \
    for (int c_ = 0; c_ < 4; ++c_) \
        glds16(srcB + c_ * 131072 + (KOFF), smem + (BUF) + 16384 + c_ * 4096 + t16); \
} while (0)

__global__ __launch_bounds__(256, 2)
void gemm_kernel(const u16* __restrict__ A, const u16* __restrict__ B,
                 const float* __restrict__ bias, float* __restrict__ C) {
    __shared__ __align__(16) char smem[65536];   // 2 x 32 KiB dbuf

    const int t = threadIdx.x;

    // T1: 2-D striped XCD swizzle (R4-proven). Grid 4096 = 64 by x 64 bx;
    // each XCD owns 8 by-rows as 4 supers of (2 by x 64 bx), by fastest:
    // ~64 co-resident blocks/XCD touch 2 A-panels + ~32 B-panels (L2-warm).
    const int bid = blockIdx.x;
    const int xcd = bid & 7;
    const int local = bid >> 3;          // 0..511
    const int super = local >> 7;        // 0..3
    const int r = local & 127;
    const int by = xcd * 8 + super * 2 + (r & 1);   // 0..63
    const int bx = r >> 1;                          // 0..63
    const int rowA0 = by * 128;
    const int rowB0 = bx * 128;

    // ---- staging addressing (inverse-swizzled global source, linear LDS) ----
    const int t16 = t * 16;
    const int ulog = (t & 7) ^ ((t >> 3) & 7);
    const int koff = (ulog >> 2) * 64 + (ulog & 3) * 16;
    const char* srcA = (const char*)A + (size_t)(rowA0 + (t >> 3)) * 4096 + koff;
    const char* srcB = (const char*)B + (size_t)(rowB0 + (t >> 3)) * 4096 + koff;

    // ---- fragment read addressing (R1's exact conflict-free form) ----
    const int lane = t & 63;
    const int wv = t >> 6;
    const int wm = wv >> 1;            // 0..1 (M half, 64 rows)
    const int wn = wv & 1;             // 0..1 (N half, 64 cols)
    const int l15 = lane & 15;
    const int quad = lane >> 4;        // 0..3
    const int l7 = l15 & 7;
    const int sx0 = (quad ^ l7) << 4;        // kk=0 unit
    const int sx1 = ((4 + quad) ^ l7) << 4;  // kk=1 unit
    const int aOff = (wm * 64 + l15) * 128;
    const int bOff = 16384 + (wn * 64 + l15) * 128;

    f32x4 acc[4][4];
#pragma unroll
    for (int i = 0; i < 4; ++i)
#pragma unroll
        for (int j = 0; j < 4; ++j) acc[i][j] = {0.f, 0.f, 0.f, 0.f};

    bf16x8 a0[4], b0[4], a1[4], b1[4];

    // ---- prologue: stage tile0 -> buf0; own-drain; BAR in loop ----
    STAGE8(0, 0);
    VMCNT0;

#pragma unroll 1
    for (int T = 0; T < NT; ++T) {
        const int bo = (T & 1) << 15;   // active buffer
        const int so = bo ^ 32768;      // inactive (receives T+1)

        FENCE; BAR; FENCE;
        if (T + 1 < NT) STAGE8(so, (T + 1) * 128);
        RD(a0, b0, bo, sx0);
        RD(a1, b1, bo, sx1);
        FENCE; LGKM8; FENCE;            // kk0 frags ready
        __builtin_amdgcn_s_setprio(1);
        MM(a0, b0);
        __builtin_amdgcn_s_setprio(0);
        FENCE; LGKM0; FENCE;            // kk1 frags ready
        __builtin_amdgcn_s_setprio(1);
        MM(a1, b1);
        __builtin_amdgcn_s_setprio(0);
        FENCE;
        VMCNT0;                         // own 8 stages for T+1 landed
    }

    // ---- epilogue: C/D col = l15, row = quad*4 + reg (m89/m91) ----
    const int col0 = rowB0 + wn * 64 + l15;
    const int row0 = rowA0 + wm * 64 + quad * 4;
    float bj[4];
#pragma unroll
    for (int j = 0; j < 4; ++j) bj[j] = bias[col0 + j * 16];
#pragma unroll
    for (int i = 0; i < 4; ++i) {
#pragma unroll
        for (int e = 0; e < 4; ++e) {
            float* crow = C + (size_t)(row0 + i * 16 + e) * NF;
#pragma unroll
            for (int j = 0; j < 4; ++j)
                __builtin_nontemporal_store(acc[i][j][e] + bj[j], crow + col0 + j * 16);
        }
    }
}

extern "C" void kernel_launch(void* const* d_in, const int* in_sizes, int n_in,
                              void* d_out, int out_size, void* d_ws, size_t ws_size,
                              hipStream_t stream) {
    const float* x      = (const float*)d_in[0];   // [4,2048,2048] fp32
    const int* packed   = (const int*)d_in[1];     // [8192,1024]
    const float* scales = (const float*)d_in[2];   // [8192,32]
    const int* zeros    = (const int*)d_in[3];     // [8192,32]
    const float* bias   = (const float*)d_in[4];   // [8192]
    float* out = (float*)d_out;                    // [8192, 8192] fp32

    // workspace: W bf16 (32 MiB) + x bf16 (32 MiB); fully rewritten every call
    u16* Wq = (u16*)d_ws;
    u16* Xb = Wq + (size_t)NF * NX;

    dequant_kernel<<<(NF * (NX / 2)) / 256, 256, 0, stream>>>(packed, scales, zeros, (uint32_t*)Wq);
    cvt_kernel<<<(MROWS * NX / 4) / 256, 256, 0, stream>>>((const float4*)x, (ushort4*)Xb);

    gemm_kernel<<<dim3((MROWS / 128) * (NF / 128)), 256, 0, stream>>>(Xb, Wq, bias, out);
}